// Round 1
// baseline (95.703 us; speedup 1.0000x reference)
//
#include <hip/hip_runtime.h>

#define NUM_CLASSES 19
#define EPS 1e-5f
#define HW 262144        // 512*512
#define HW4 65536        // HW/4

// counts layout in d_ws: [0..18] inter, [19..37] count_y, [38..56] count_p
__global__ void __launch_bounds__(256)
dice_hist_kernel(const float* __restrict__ y_pred,
                 const int* __restrict__ y,
                 unsigned int* __restrict__ counts,
                 int n_vec) {
    __shared__ unsigned int s_inter[NUM_CLASSES];
    __shared__ unsigned int s_cy[NUM_CLASSES];
    __shared__ unsigned int s_cp[NUM_CLASSES];
    const int tid = threadIdx.x;
    if (tid < NUM_CLASSES) { s_inter[tid] = 0u; s_cy[tid] = 0u; s_cp[tid] = 0u; }
    __syncthreads();

    for (int pv = blockIdx.x * blockDim.x + tid; pv < n_vec;
         pv += gridDim.x * blockDim.x) {
        const int b   = pv >> 16;        // pv / HW4  (HW4 = 65536)
        const int hw4 = pv & 65535;      // pv % HW4
        const size_t base = (size_t)b * NUM_CLASSES * HW + (size_t)hw4 * 4;

        // argmax over 19 class planes, 4 pixels at a time
        float4 best = *reinterpret_cast<const float4*>(y_pred + base);
        int bcx = 0, bcy = 0, bcz = 0, bcw = 0;
        #pragma unroll
        for (int c = 1; c < NUM_CLASSES; ++c) {
            float4 v = *reinterpret_cast<const float4*>(y_pred + base + (size_t)c * HW);
            if (v.x > best.x) { best.x = v.x; bcx = c; }
            if (v.y > best.y) { best.y = v.y; bcy = c; }
            if (v.z > best.z) { best.z = v.z; bcz = c; }
            if (v.w > best.w) { best.w = v.w; bcw = c; }
        }

        const int4 lab = *reinterpret_cast<const int4*>(y + (size_t)pv * 4);

        atomicAdd(&s_cy[lab.x], 1u);
        atomicAdd(&s_cy[lab.y], 1u);
        atomicAdd(&s_cy[lab.z], 1u);
        atomicAdd(&s_cy[lab.w], 1u);
        atomicAdd(&s_cp[bcx], 1u);
        atomicAdd(&s_cp[bcy], 1u);
        atomicAdd(&s_cp[bcz], 1u);
        atomicAdd(&s_cp[bcw], 1u);
        if (lab.x == bcx) atomicAdd(&s_inter[lab.x], 1u);
        if (lab.y == bcy) atomicAdd(&s_inter[lab.y], 1u);
        if (lab.z == bcz) atomicAdd(&s_inter[lab.z], 1u);
        if (lab.w == bcw) atomicAdd(&s_inter[lab.w], 1u);
    }

    __syncthreads();
    if (tid < NUM_CLASSES) {
        unsigned int vi = s_inter[tid], vy = s_cy[tid], vp = s_cp[tid];
        if (vi) atomicAdd(&counts[tid], vi);
        if (vy) atomicAdd(&counts[NUM_CLASSES + tid], vy);
        if (vp) atomicAdd(&counts[2 * NUM_CLASSES + tid], vp);
    }
}

__global__ void dice_finalize(const unsigned int* __restrict__ counts,
                              float* __restrict__ out) {
    const int lane = threadIdx.x;
    float d = 0.0f;
    if (lane < NUM_CLASSES) {
        const float inter = (float)counts[lane];
        const float cy    = (float)counts[NUM_CLASSES + lane];
        const float cp    = (float)counts[2 * NUM_CLASSES + lane];
        const float uni   = cy + cp - inter;
        d = (2.0f * inter + EPS) / (uni + EPS);
    }
    #pragma unroll
    for (int off = 32; off > 0; off >>= 1) d += __shfl_down(d, off);
    if (lane == 0) out[0] = 1.0f - d * (1.0f / (float)NUM_CLASSES);
}

extern "C" void kernel_launch(void* const* d_in, const int* in_sizes, int n_in,
                              void* d_out, int out_size, void* d_ws, size_t ws_size,
                              hipStream_t stream) {
    const float* y_pred = (const float*)d_in[0];
    const int*   y      = (const int*)d_in[1];
    float*       out    = (float*)d_out;
    unsigned int* counts = (unsigned int*)d_ws;

    // zero the 3x19 counter workspace (harness poisons d_ws with 0xAA)
    hipMemsetAsync(counts, 0, 3 * NUM_CLASSES * sizeof(unsigned int), stream);

    const int n_pix = in_sizes[1];     // 16*512*512 = 4,194,304
    const int n_vec = n_pix / 4;       // 1,048,576

    const int block = 256;
    const int grid  = 2048;            // 8 blocks/CU target, grid-stride covers rest
    dice_hist_kernel<<<grid, block, 0, stream>>>(y_pred, y, counts, n_vec);
    dice_finalize<<<1, 64, 0, stream>>>(counts, out);
}

// Round 2
// 76.674 us; speedup vs baseline: 1.2482x; 1.2482x over previous
//
#include <hip/hip_runtime.h>

#define NCLS 19
#define CM_BINS (NCLS * NCLS)   // 361
#define EPS 1e-5f
#define HW 262144               // 512*512
#define HW4 65536               // HW/4

typedef float f32x4 __attribute__((ext_vector_type(4)));
typedef int   i32x4 __attribute__((ext_vector_type(4)));

// d_ws: cm[361] confusion-matrix counts, cm[y*19 + pred]
__global__ void __launch_bounds__(256)
dice_cm_kernel(const float* __restrict__ y_pred,
               const int* __restrict__ y,
               unsigned int* __restrict__ cm,
               int n_vec) {
    __shared__ unsigned int s_cm[CM_BINS];
    const int tid = threadIdx.x;
    for (int i = tid; i < CM_BINS; i += 256) s_cm[i] = 0u;
    __syncthreads();

    for (int pv = blockIdx.x * 256 + tid; pv < n_vec; pv += gridDim.x * 256) {
        const int b   = pv >> 16;        // pv / HW4
        const int hw4 = pv & 65535;      // pv % HW4
        const float* p = y_pred + (size_t)b * ((size_t)NCLS * HW) + (size_t)hw4 * 4;

        // argmax over 19 class planes, 4 pixels at a time (strict > keeps
        // lowest class on ties, matching jnp.argmax first-occurrence)
        f32x4 best = __builtin_nontemporal_load(reinterpret_cast<const f32x4*>(p));
        int bcx = 0, bcy = 0, bcz = 0, bcw = 0;
        #pragma unroll
        for (int c = 1; c < NCLS; ++c) {
            f32x4 v = __builtin_nontemporal_load(
                reinterpret_cast<const f32x4*>(p + (size_t)c * HW));
            if (v.x > best.x) { best.x = v.x; bcx = c; }
            if (v.y > best.y) { best.y = v.y; bcy = c; }
            if (v.z > best.z) { best.z = v.z; bcz = c; }
            if (v.w > best.w) { best.w = v.w; bcw = c; }
        }

        const i32x4 lab = __builtin_nontemporal_load(
            reinterpret_cast<const i32x4*>(y + (size_t)pv * 4));

        // one atomic per pixel, spread over 361 bins
        atomicAdd(&s_cm[lab.x * NCLS + bcx], 1u);
        atomicAdd(&s_cm[lab.y * NCLS + bcy], 1u);
        atomicAdd(&s_cm[lab.z * NCLS + bcz], 1u);
        atomicAdd(&s_cm[lab.w * NCLS + bcw], 1u);
    }

    __syncthreads();
    for (int i = tid; i < CM_BINS; i += 256) {
        const unsigned int v = s_cm[i];
        if (v) atomicAdd(&cm[i], v);
    }
}

__global__ void dice_finalize(const unsigned int* __restrict__ cm,
                              float* __restrict__ out) {
    const int lane = threadIdx.x;
    float d = 0.0f;
    if (lane < NCLS) {
        float cy = 0.0f, cp = 0.0f;
        #pragma unroll
        for (int j = 0; j < NCLS; ++j) {
            cy += (float)cm[lane * NCLS + j];   // row sum: |y==lane|
            cp += (float)cm[j * NCLS + lane];   // col sum: |pred==lane|
        }
        const float inter = (float)cm[lane * NCLS + lane];
        const float uni   = cy + cp - inter;
        d = (2.0f * inter + EPS) / (uni + EPS);
    }
    #pragma unroll
    for (int off = 32; off > 0; off >>= 1) d += __shfl_down(d, off);
    if (lane == 0) out[0] = 1.0f - d * (1.0f / (float)NCLS);
}

extern "C" void kernel_launch(void* const* d_in, const int* in_sizes, int n_in,
                              void* d_out, int out_size, void* d_ws, size_t ws_size,
                              hipStream_t stream) {
    const float* y_pred = (const float*)d_in[0];
    const int*   y      = (const int*)d_in[1];
    float*       out    = (float*)d_out;
    unsigned int* cm    = (unsigned int*)d_ws;

    // zero the 361-bin confusion matrix (harness poisons d_ws with 0xAA)
    hipMemsetAsync(cm, 0, CM_BINS * sizeof(unsigned int), stream);

    const int n_pix = in_sizes[1];     // 16*512*512 = 4,194,304
    const int n_vec = n_pix / 4;       // 1,048,576

    const int block = 256;
    const int grid  = 2048;            // 8 blocks/CU, 2 grid-stride iters/thread
    dice_cm_kernel<<<grid, block, 0, stream>>>(y_pred, y, cm, n_vec);
    dice_finalize<<<1, 64, 0, stream>>>(cm, out);
}